// Round 8
// baseline (30.533 us; speedup 1.0000x reference)
//
#include <hip/hip_runtime.h>

#define S_TOT 2048
#define B_SZ  32
#define I_SZ  256
#define O_SZ  80

typedef _Float16 f16x8 __attribute__((ext_vector_type(8)));
typedef float    f32x4 __attribute__((ext_vector_type(4)));

// Round-7 base (static grid, 1 block = 1 subsystem, 5 waves, LDS = X only,
// XOR-swizzle, ragged-K + ragged-O exact skips) with the W-load phase
// restructured for memory-level parallelism. Round-4 evidence VGPR=40 shows
// the compiler SANK the W loads past __syncthreads into the MFMA loop
// (wf[8]=32 VGPR can't fit in 40) -> W MLP ~= 2. Fix: (a) two half-batches
// of 4 k-chunks, issue-all-8-loads then convert; (b) keep-alive inline asm
// pins wf materialization BEFORE the barrier (can't sink); (c)
// launch_bounds(320,6) raises the VGPR cap to ~84 so the transient raw
// f32 regs fit. Occupancy 30->20 waves/CU, per-wave outstanding ~3->~16.
__device__ __forceinline__ float ftanh(float v) {
  float e = __expf(2.0f * v);
  return 1.0f - __fdividef(2.0f, e + 1.0f);
}

__device__ __forceinline__ f16x8 cvt8(f32x4 lo, f32x4 hi) {
  f16x8 h;
  h[0] = (_Float16)lo[0]; h[1] = (_Float16)lo[1];
  h[2] = (_Float16)lo[2]; h[3] = (_Float16)lo[3];
  h[4] = (_Float16)hi[0]; h[5] = (_Float16)hi[1];
  h[6] = (_Float16)hi[2]; h[7] = (_Float16)hi[3];
  return h;
}

__global__ __launch_bounds__(320, 6) void dcell_kernel(
    const float* __restrict__ x,        // [S, 32, 256]
    const float* __restrict__ W,        // [S, 80, 256]
    const float* __restrict__ bias,     // [S, 80]
    const float* __restrict__ gamma,    // [S, 80]
    const float* __restrict__ beta,     // [S, 80]
    const float* __restrict__ in_mask,  // [S, 256]
    const float* __restrict__ out_mask, // [S, 80]
    float* __restrict__ out)            // [S, 32, 80]
{
  __shared__ char Xs[16384];  // 32 rows * 512B

  const int s   = blockIdx.x;
  const int tid = threadIdx.x;

  const int w  = tid >> 6;   // wave 0..4 -> o-chunk
  const int l  = tid & 63;
  const int m  = l & 15;     // A row / B col within tile
  const int ks = l >> 4;     // k-slice 0..3
  const int ob = w * 16;
  const int o  = ob + m;
  const int swz = (m & 7) << 4;

  // ---- active K-chunk count (block-uniform; in_mask is prefix-ones)
  const float* im = in_mask + (size_t)s * I_SZ;
  float msum = im[0] + im[32] + im[64] + im[96] +
               im[128] + im[160] + im[192] + im[224];
  const int kcmax = (int)(msum + 0.5f);   // 1..8
  const int Kact  = kcmax * 32;

  const float* omp = out_mask + (size_t)s * O_SZ;
  const bool wave_act = (omp[ob] != 0.0f);   // prefix-ones
  const bool lane_act = (omp[o]  != 0.0f);

  // hoist epilogue scalars so their latency hides under staging
  const float bv  = bias[s * O_SZ + o];
  const float gm  = gamma[s * O_SZ + o];
  const float be  = beta[s * O_SZ + o];
  const float om  = omp[o];

  // ---- stage X: f32 -> f16, swizzled; 1024 x 32B chunks, unrolled.
  // chunk t: row r = t>>5, cols c = (t&31)*8 .. +8 (Kact multiple of 32
  // -> both halves of a chunk are on the same side of the guard).
  {
    const float* xg = x + (size_t)s * (B_SZ * I_SZ);
#pragma unroll
    for (int i = 0; i < 3; ++i) {
      int t = tid + i * 320;
      int r = t >> 5, c = (t & 31) * 8;
      if (c < Kact) {
        f32x4 lo = *(const f32x4*)(xg + t * 8);
        f32x4 hi = *(const f32x4*)(xg + t * 8 + 4);
        int off = r * 512 + ((c * 2) ^ ((r & 7) << 4));
        *(f16x8*)(Xs + off) = cvt8(lo, hi);
      }
    }
    if (tid < 64) {
      int t = 960 + tid;
      int r = t >> 5, c = (t & 31) * 8;
      if (c < Kact) {
        f32x4 lo = *(const f32x4*)(xg + t * 8);
        f32x4 hi = *(const f32x4*)(xg + t * 8 + 4);
        int off = r * 512 + ((c * 2) ^ ((r & 7) << 4));
        *(f16x8*)(Xs + off) = cvt8(lo, hi);
      }
    }
  }

  // ---- W fragments: global -> reg, f32 -> f16; two half-batches of 4
  // k-chunks: issue all 8 predicated loads, THEN convert (MLP=8/half).
  // Lane (m,ks) of wave w holds W[o][kc*32 + ks*8 .. +8). Combined per-lane
  // predicate (lane_act && kc<kcmax): masked lanes/chunks skip via exec
  // mask -> no wasted traffic, no uniform-branch serialization.
  f16x8 wf[8];
  {
    const float* wgp = W + ((size_t)s * O_SZ + o) * I_SZ + ks * 8;
    const int nact = lane_act ? kcmax : 0;
#pragma unroll
    for (int h = 0; h < 2; ++h) {
      f32x4 lo[4], hi[4];
#pragma unroll
      for (int j = 0; j < 4; ++j) {
        int kc = h * 4 + j;
        lo[j] = (f32x4){0.f, 0.f, 0.f, 0.f};
        hi[j] = (f32x4){0.f, 0.f, 0.f, 0.f};
        if (kc < nact) {
          lo[j] = *(const f32x4*)(wgp + kc * 32);
          hi[j] = *(const f32x4*)(wgp + kc * 32 + 4);
        }
      }
#pragma unroll
      for (int j = 0; j < 4; ++j)
        wf[h * 4 + j] = cvt8(lo[j], hi[j]);
    }
    // pin wf materialization BEFORE the barrier so the loads can't be sunk
    // into the MFMA loop (round-4 VGPR=40 proved the compiler does this).
#pragma unroll
    for (int kc = 0; kc < 8; ++kc)
      asm volatile("" :: "v"(wf[kc]));
  }
  __syncthreads();

  float* og = out + (size_t)s * (B_SZ * O_SZ) + o;

  if (wave_act) {
    // ---- per-wave GEMM: two 16x16 tiles (b=0..15, b=16..31), K=Kact
    f32x4 acc0 = {0.f, 0.f, 0.f, 0.f};
    f32x4 acc1 = {0.f, 0.f, 0.f, 0.f};
    const char* xr0 = Xs + m * 512;
    const char* xr1 = Xs + (m + 16) * 512;   // (m+16)&7 == m&7
#pragma unroll
    for (int kc = 0; kc < 8; ++kc) {
      if (kc < kcmax) {
        int kb = (kc * 64 + ks * 16) ^ swz;
        f16x8 a0 = *(const f16x8*)(xr0 + kb);
        f16x8 a1 = *(const f16x8*)(xr1 + kb);
        acc0 = __builtin_amdgcn_mfma_f32_16x16x32_f16(a0, wf[kc], acc0, 0, 0, 0);
        acc1 = __builtin_amdgcn_mfma_f32_16x16x32_f16(a1, wf[kc], acc1, 0, 0, 0);
      }
    }

    // ---- epilogue: bias, tanh, BN over b (in-register), mask, store.
    // C layout (m89): col = lane&15, row = (lane>>4)*4 + reg.
    float t0[4], t1[4];
    float sum = 0.f;
#pragma unroll
    for (int r = 0; r < 4; ++r) {
      t0[r] = ftanh(acc0[r] + bv);
      t1[r] = ftanh(acc1[r] + bv);
      sum += t0[r] + t1[r];
    }
    sum += __shfl_xor(sum, 16);
    sum += __shfl_xor(sum, 32);
    const float mean = sum * (1.0f / 32.0f);

    float vs = 0.f;
#pragma unroll
    for (int r = 0; r < 4; ++r) {
      float d0 = t0[r] - mean, d1 = t1[r] - mean;
      vs += d0 * d0 + d1 * d1;
    }
    vs += __shfl_xor(vs, 16);
    vs += __shfl_xor(vs, 32);
    const float rstd = rsqrtf(vs * (1.0f / 32.0f) + 1e-5f);

    const float g = gm * rstd;

#pragma unroll
    for (int r = 0; r < 4; ++r) {
      int b0 = ks * 4 + r;
      og[(size_t)b0 * O_SZ]        = ((t0[r] - mean) * g + be) * om;
      og[(size_t)(b0 + 16) * O_SZ] = ((t1[r] - mean) * g + be) * om;
    }
  } else {
    // fully-masked o-chunk: output exactly 0 (d_out is poisoned).
#pragma unroll
    for (int r = 0; r < 4; ++r) {
      int b0 = ks * 4 + r;
      og[(size_t)b0 * O_SZ]        = 0.f;
      og[(size_t)(b0 + 16) * O_SZ] = 0.f;
    }
  }
}

extern "C" void kernel_launch(void* const* d_in, const int* in_sizes, int n_in,
                              void* d_out, int out_size, void* d_ws, size_t ws_size,
                              hipStream_t stream) {
  const float* x        = (const float*)d_in[0];
  const float* W        = (const float*)d_in[1];
  const float* bias     = (const float*)d_in[2];
  const float* gamma    = (const float*)d_in[3];
  const float* beta     = (const float*)d_in[4];
  const float* in_mask  = (const float*)d_in[5];
  const float* out_mask = (const float*)d_in[6];
  float* out = (float*)d_out;

  dcell_kernel<<<dim3(S_TOT), dim3(320), 0, stream>>>(
      x, W, bias, gamma, beta, in_mask, out_mask, out);
}